// Round 2
// baseline (304.586 us; speedup 1.0000x reference)
//
#include <hip/hip_runtime.h>
#include <math.h>

// ---------------- problem constants ----------------
// B=32, S=32, EMB=300, AUDIO=74, HID=128, D1=D2=16, DIM=256, UNITS=128, CELL=64

// ---------------- workspace layout (float offsets) ----------------
// xw partials (2 x 1024 x 512), h (1024x128), X=[real|imag] (1024x512),
// weight (1024), V'' (256x512), P partials (4 x 1024 x 256)
static constexpr unsigned XW0_OFF  = 0u;
static constexpr unsigned XW1_OFF  = 524288u;            // 1024*512
static constexpr unsigned HOUT_OFF = 1048576u;
static constexpr unsigned XMAT_OFF = HOUT_OFF + 131072u; // 1179648
static constexpr unsigned WT_OFF   = XMAT_OFF + 524288u; // 1703936
static constexpr unsigned VPP_OFF  = WT_OFF + 1024u;     // 1704960
static constexpr unsigned PP_OFF   = VPP_OFF + 131072u;  // 1836032
static constexpr unsigned PP_HALF  = 262144u;            // 1024*256

// =====================================================================
// K1: xw[r][j] = sum_k lut[word[r]][k] * w_ih[j][k]  (+ b_ih + b_hh on kq==0)
//     k split in two halves [0,152) and [152,300); 64x64 tiles, 4x4 micro.
//     Block 256 additionally builds V'' (256 x 512) measurement matrix.
// =====================================================================
__global__ __launch_bounds__(256) void k1_xw_gemm(
    const int* __restrict__ widx, const float* __restrict__ lut,
    const float* __restrict__ w_ih, const float* __restrict__ b_ih,
    const float* __restrict__ b_hh,
    const float* __restrict__ mr, const float* __restrict__ mi,
    float* __restrict__ ws)
{
  const int bid = blockIdx.x;
  const int t = threadIdx.x;

  if (bid >= 256) {
    // ---- V'' builder: row 2u = [vr_u | vi_u], row 2u+1 = [-vi_u | vr_u]
    __shared__ float kn_l[128];
    if (t < 128) {
      float ssum = 0.f;
      for (int d = 0; d < 256; ++d) {
        float r = mr[t * 256 + d], ii = mi[t * 256 + d];
        ssum += r * r + ii * ii;
      }
      kn_l[t] = sqrtf(ssum) + 1e-10f;
    }
    __syncthreads();
    float* vpp = ws + VPP_OFF;
    for (int e = t; e < 256 * 512; e += 256) {
      int c = e >> 9, k = e & 511, u = c >> 1;
      float inv = 1.0f / kn_l[u];
      float v;
      if ((c & 1) == 0) v = (k < 256 ? mr[u * 256 + k] : mi[u * 256 + k - 256]) * inv;
      else              v = (k < 256 ? -mi[u * 256 + k] : mr[u * 256 + k - 256]) * inv;
      vpp[e] = v;
    }
    return;
  }

  const int rb = bid & 15, cb = (bid >> 4) & 7, kq = bid >> 7;
  const int R = rb * 64, C = cb * 64;
  const int kbase_g = kq * 152;
  const int ktot = kq ? 148 : 152;

  __shared__ alignas(16) float As[32][68];
  __shared__ alignas(16) float Ws[32][68];

  float acc[4][4] = {};
  const int r0 = (t & 15) * 4, j0 = (t >> 4) * 4;

  for (int kt = 0; kt < 5; ++kt) {
    int kl = ktot - kt * 32; if (kl > 32) kl = 32;   // 32,32,32,32,24/20 (all %4==0)
    #pragma unroll
    for (int pass = 0; pass < 2; ++pass) {
      int rr = (t >> 3) + pass * 32;
      int kk4 = (t & 7) * 4;
      float4 av = make_float4(0.f, 0.f, 0.f, 0.f);
      float4 wv = make_float4(0.f, 0.f, 0.f, 0.f);
      if (kk4 < kl) {
        int gk = kbase_g + kt * 32 + kk4;
        int word = widx[R + rr];
        av = *(const float4*)&lut[word * 300 + gk];
        wv = *(const float4*)&w_ih[(C + rr) * 300 + gk];
      }
      As[kk4 + 0][rr] = av.x; As[kk4 + 1][rr] = av.y;
      As[kk4 + 2][rr] = av.z; As[kk4 + 3][rr] = av.w;
      Ws[kk4 + 0][rr] = wv.x; Ws[kk4 + 1][rr] = wv.y;
      Ws[kk4 + 2][rr] = wv.z; Ws[kk4 + 3][rr] = wv.w;
    }
    __syncthreads();
    #pragma unroll
    for (int k = 0; k < 32; ++k) {
      float4 a4 = *(const float4*)&As[k][r0];
      float4 w4 = *(const float4*)&Ws[k][j0];
      float ar[4] = {a4.x, a4.y, a4.z, a4.w};
      float wr[4] = {w4.x, w4.y, w4.z, w4.w};
      #pragma unroll
      for (int i2 = 0; i2 < 4; ++i2)
        #pragma unroll
        for (int j2 = 0; j2 < 4; ++j2)
          acc[i2][j2] = fmaf(ar[i2], wr[j2], acc[i2][j2]);
    }
    __syncthreads();
  }

  float* xw = ws + (kq ? XW1_OFF : XW0_OFF);
  #pragma unroll
  for (int i2 = 0; i2 < 4; ++i2) {
    int row = R + r0 + i2, col = C + j0;
    float4 v = make_float4(acc[i2][0], acc[i2][1], acc[i2][2], acc[i2][3]);
    if (kq == 0) {
      v.x += b_ih[col + 0] + b_hh[col + 0];
      v.y += b_ih[col + 1] + b_hh[col + 1];
      v.z += b_ih[col + 2] + b_hh[col + 2];
      v.w += b_ih[col + 3] + b_hh[col + 3];
    }
    *(float4*)&xw[row * 512 + col] = v;
  }
}

// =====================================================================
// K2: LSTM recurrence. One block per batch element, 512 threads.
//     thread = (jj = gate-unit 0..127, kq = k-quarter 0..3).
//     w_hh weight-stationary in VGPRs (4 gates x 32 k = 128 regs).
//     h double-buffered in LDS; shuffle-reduce partials over kq.
// =====================================================================
__global__ __launch_bounds__(512, 2) void k2_lstm(
    const float* __restrict__ w_hh, float* __restrict__ ws)
{
  const int b = blockIdx.x;
  const int t = threadIdx.x;
  const int jj = t >> 2;     // 0..127
  const int kq = t & 3;      // 0..3

  float4 wreg[4][8];
  #pragma unroll
  for (int g = 0; g < 4; ++g) {
    const float* wp = w_hh + (jj + 128 * g) * 128 + kq * 32;
    #pragma unroll
    for (int i = 0; i < 8; ++i) wreg[g][i] = *(const float4*)&wp[i * 4];
  }

  __shared__ alignas(16) float hbuf[2][128];
  if (t < 128) hbuf[0][t] = 0.f;

  const float* xw0 = ws + XW0_OFF;
  const float* xw1 = ws + XW1_OFF;
  float* hout = ws + HOUT_OFF;

  float c = 0.f;
  float hhist[32];
  __syncthreads();

  for (int s = 0; s < 32; ++s) {
    const int bs = b * 32 + s;
    float xg0 = 0.f, xg1 = 0.f, xg2 = 0.f, xg3 = 0.f;
    if (kq == 0) {
      int base = bs * 512 + jj;
      xg0 = xw0[base +   0] + xw1[base +   0];
      xg1 = xw0[base + 128] + xw1[base + 128];
      xg2 = xw0[base + 256] + xw1[base + 256];
      xg3 = xw0[base + 384] + xw1[base + 384];
    }
    const float4* hb = (const float4*)hbuf[s & 1] + kq * 8;
    float a0 = 0.f, a1 = 0.f, a2 = 0.f, a3 = 0.f;
    #pragma unroll
    for (int i = 0; i < 8; ++i) {
      float4 h4 = hb[i];
      a0 = fmaf(wreg[0][i].x, h4.x, fmaf(wreg[0][i].y, h4.y, fmaf(wreg[0][i].z, h4.z, fmaf(wreg[0][i].w, h4.w, a0))));
      a1 = fmaf(wreg[1][i].x, h4.x, fmaf(wreg[1][i].y, h4.y, fmaf(wreg[1][i].z, h4.z, fmaf(wreg[1][i].w, h4.w, a1))));
      a2 = fmaf(wreg[2][i].x, h4.x, fmaf(wreg[2][i].y, h4.y, fmaf(wreg[2][i].z, h4.z, fmaf(wreg[2][i].w, h4.w, a2))));
      a3 = fmaf(wreg[3][i].x, h4.x, fmaf(wreg[3][i].y, h4.y, fmaf(wreg[3][i].z, h4.z, fmaf(wreg[3][i].w, h4.w, a3))));
    }
    a0 += __shfl_xor(a0, 1); a0 += __shfl_xor(a0, 2);
    a1 += __shfl_xor(a1, 1); a1 += __shfl_xor(a1, 2);
    a2 += __shfl_xor(a2, 1); a2 += __shfl_xor(a2, 2);
    a3 += __shfl_xor(a3, 1); a3 += __shfl_xor(a3, 2);
    if (kq == 0) {
      float gi = xg0 + a0, gf = xg1 + a1, gg = xg2 + a2, go = xg3 + a3;
      float si = 1.f / (1.f + __expf(-gi));
      float sf = 1.f / (1.f + __expf(-gf));
      float tg = 1.f - 2.f / (1.f + __expf(2.f * gg));
      float so = 1.f / (1.f + __expf(-go));
      c = sf * c + si * tg;
      float tc = 1.f - 2.f / (1.f + __expf(2.f * c));
      float hn = so * tc;
      hbuf[(s + 1) & 1][jj] = hn;
      hhist[s] = hn;
    }
    __syncthreads();
  }
  if (kq == 0) {
    #pragma unroll
    for (int s = 0; s < 32; ++s) hout[(b * 32 + s) * 128 + jj] = hhist[s];
  }
}

// =====================================================================
// K3: per (b,s): amp0 = h@w_lin.T+b_lin; audio MLP -> amp1; norms; phases;
//     tpr/tpi x r1/i1 outer products -> X=[real|imag] row; weight scalar.
// =====================================================================
__global__ __launch_bounds__(256) void k3_mix(
    const int* __restrict__ widx, const float* __restrict__ audio,
    const float* __restrict__ ph0t, const float* __restrict__ ph1t,
    const float* __restrict__ w_lin, const float* __restrict__ b_lin,
    const float* __restrict__ w1, const float* __restrict__ b1,
    const float* __restrict__ w2, const float* __restrict__ b2,
    const float* __restrict__ w3, const float* __restrict__ b3,
    const float* __restrict__ modw, float* __restrict__ ws)
{
  const int bs = blockIdx.x;
  const int t = threadIdx.x;
  __shared__ float amp0[16], a1s[16], a2s[16], amp1[16];
  __shared__ float tpr[16], tpi[16], r1s[16], i1s[16];
  __shared__ float nn[2];

  const float* hrow = ws + HOUT_OFF + bs * 128;
  if (t < 16) {
    float acc = b_lin[t];
    for (int u = 0; u < 128; ++u) acc = fmaf(hrow[u], w_lin[t * 128 + u], acc);
    amp0[t] = acc;
  } else if (t >= 64 && t < 80) {
    int d = t - 64;
    float acc = b1[d];
    for (int k = 0; k < 74; ++k) acc = fmaf(audio[bs * 74 + k], w1[d * 74 + k], acc);
    a1s[d] = fmaxf(acc, 0.f);
  }
  __syncthreads();
  if (t < 16) {
    float acc = b2[t];
    #pragma unroll
    for (int k = 0; k < 16; ++k) acc = fmaf(a1s[k], w2[t * 16 + k], acc);
    a2s[t] = fmaxf(acc, 0.f);
  }
  __syncthreads();
  if (t < 16) {
    float acc = b3[t];
    #pragma unroll
    for (int k = 0; k < 16; ++k) acc = fmaf(a2s[k], w3[t * 16 + k], acc);
    amp1[t] = fmaxf(acc, 0.f);
  }
  __syncthreads();
  if (t == 0) {
    float sq = 0.f;
    #pragma unroll
    for (int d = 0; d < 16; ++d) sq += amp0[d] * amp0[d];
    nn[0] = sqrtf(sq);
  } else if (t == 64) {
    float sq = 0.f;
    #pragma unroll
    for (int d = 0; d < 16; ++d) sq += amp1[d] * amp1[d];
    nn[1] = sqrtf(sq);
  }
  __syncthreads();
  const int word = widx[bs];
  if (t < 16) {
    float k0 = amp0[t] / (nn[0] + 1e-10f);
    float ph = ph0t[word * 16 + t];
    float cc = cosf(ph), ssn = sinf(ph);
    tpr[t] = k0 * (cc - ssn);       // r0 - i0
    tpi[t] = k0 * (cc + ssn);       // r0 + i0
  } else if (t >= 64 && t < 80) {
    int d = t - 64;
    float k1 = amp1[d] / (nn[1] + 1e-10f);
    float ph = ph1t[word * 16 + d];
    r1s[d] = k1 * cosf(ph);
    i1s[d] = k1 * sinf(ph);
  } else if (t == 128) {
    float e0 = __expf(modw[0]), e1 = __expf(modw[1]);
    float mw0 = e0 / (e0 + e1);
    ws[WT_OFF + bs] = mw0 * nn[0] + (1.f - mw0) * nn[1];
  }
  __syncthreads();
  const int i2 = t >> 4, j2 = t & 15;
  float rr = tpr[i2] * r1s[j2] - tpi[i2] * i1s[j2];
  float im = tpr[i2] * i1s[j2] + tpi[i2] * r1s[j2];
  float* X = ws + XMAT_OFF;
  X[bs * 512 + t] = rr;
  X[bs * 512 + 256 + t] = im;
}

// =====================================================================
// K4: P[r][c] = sum_k X[r][k] * V''[c][k]   (1024 x 256, k=512 split x4)
//     writes per-kq partials; 64x64 tiles, 4x4 micro.
// =====================================================================
__global__ __launch_bounds__(256) void k4_meas(float* __restrict__ ws)
{
  const int bid = blockIdx.x, t = threadIdx.x;
  const int rb = bid & 15, cb = (bid >> 4) & 3, kq = bid >> 6;
  const int R = rb * 64, C = cb * 64;
  const float* X = ws + XMAT_OFF;
  const float* V = ws + VPP_OFF;
  __shared__ alignas(16) float Xs[32][68];
  __shared__ alignas(16) float Vs[32][68];
  float acc[4][4] = {};
  const int r0 = (t & 15) * 4, j0 = (t >> 4) * 4;

  for (int kt = 0; kt < 4; ++kt) {
    #pragma unroll
    for (int pass = 0; pass < 2; ++pass) {
      int rr = (t >> 3) + pass * 32;
      int kk4 = (t & 7) * 4;
      int gk = kq * 128 + kt * 32 + kk4;
      float4 xv = *(const float4*)&X[(R + rr) * 512 + gk];
      float4 vv = *(const float4*)&V[(C + rr) * 512 + gk];
      Xs[kk4 + 0][rr] = xv.x; Xs[kk4 + 1][rr] = xv.y;
      Xs[kk4 + 2][rr] = xv.z; Xs[kk4 + 3][rr] = xv.w;
      Vs[kk4 + 0][rr] = vv.x; Vs[kk4 + 1][rr] = vv.y;
      Vs[kk4 + 2][rr] = vv.z; Vs[kk4 + 3][rr] = vv.w;
    }
    __syncthreads();
    #pragma unroll
    for (int k = 0; k < 32; ++k) {
      float4 a4 = *(const float4*)&Xs[k][r0];
      float4 w4 = *(const float4*)&Vs[k][j0];
      float ar[4] = {a4.x, a4.y, a4.z, a4.w};
      float wr[4] = {w4.x, w4.y, w4.z, w4.w};
      #pragma unroll
      for (int i2 = 0; i2 < 4; ++i2)
        #pragma unroll
        for (int j2 = 0; j2 < 4; ++j2)
          acc[i2][j2] = fmaf(ar[i2], wr[j2], acc[i2][j2]);
    }
    __syncthreads();
  }
  float* Pp = ws + PP_OFF + (unsigned)kq * PP_HALF;
  #pragma unroll
  for (int i2 = 0; i2 < 4; ++i2) {
    float4 v = make_float4(acc[i2][0], acc[i2][1], acc[i2][2], acc[i2][3]);
    *(float4*)&Pp[(R + r0 + i2) * 256 + C + j0] = v;
  }
}

// =====================================================================
// K5: per b: p[s][u] = P[2u]^2 + P[2u+1]^2 (sum kq partials);
//     n-gram softmax mixes (n=1,3 with zero-padded softmax), max-pool,
//     final 128->64->64->1 MLP.
// =====================================================================
__global__ __launch_bounds__(128) void k5_final(
    const float* __restrict__ fw1, const float* __restrict__ fb1,
    const float* __restrict__ fw2, const float* __restrict__ fb2,
    const float* __restrict__ fw3, const float* __restrict__ fb3,
    const float* __restrict__ ws, float* __restrict__ out)
{
  const int b = blockIdx.x, t = threadIdx.x;
  __shared__ float ewt[34], feat[128], y1[64], y2[64];
  if (t < 32) ewt[t] = expf(ws[WT_OFF + b * 32 + t]);
  if (t == 0) { ewt[32] = 1.f; ewt[33] = 1.f; }
  __syncthreads();

  const float* Pp = ws + PP_OFF;
  float p[32];
  #pragma unroll
  for (int s = 0; s < 32; ++s) {
    int bs = b * 32 + s;
    float A = 0.f, Bv = 0.f;
    #pragma unroll
    for (int kq = 0; kq < 4; ++kq) {
      A  += Pp[kq * PP_HALF + bs * 256 + 2 * t];
      Bv += Pp[kq * PP_HALF + bs * 256 + 2 * t + 1];
    }
    p[s] = A * A + Bv * Bv;
  }
  float m = -1e30f;
  #pragma unroll
  for (int s = 0; s < 32; ++s) m = fmaxf(m, p[s]);        // n=1 (softmax of 1 elem = 1)
  #pragma unroll
  for (int s = 0; s < 32; ++s) {                          // n=3, zero-padded softmax
    float e0 = ewt[s], e1 = ewt[s + 1], e2 = ewt[s + 2];
    float num = e0 * p[s];
    if (s + 1 < 32) num += e1 * p[s + 1];
    if (s + 2 < 32) num += e2 * p[s + 2];
    m = fmaxf(m, num / (e0 + e1 + e2));
  }
  feat[t] = m;
  __syncthreads();
  if (t < 64) {
    float acc = fb1[t];
    for (int k = 0; k < 128; ++k) acc = fmaf(feat[k], fw1[t * 128 + k], acc);
    y1[t] = fmaxf(acc, 0.f);
  }
  __syncthreads();
  if (t < 64) {
    float acc = fb2[t];
    #pragma unroll
    for (int k = 0; k < 64; ++k) acc = fmaf(y1[k], fw2[t * 64 + k], acc);
    y2[t] = fmaxf(acc, 0.f);
  }
  __syncthreads();
  if (t == 0) {
    float acc = fb3[0];
    #pragma unroll
    for (int k = 0; k < 64; ++k) acc = fmaf(y2[k], fw3[k], acc);
    out[b] = acc;
  }
}

// =====================================================================
extern "C" void kernel_launch(void* const* d_in, const int* in_sizes, int n_in,
                              void* d_out, int out_size, void* d_ws, size_t ws_size,
                              hipStream_t stream) {
  const int*   widx  = (const int*)d_in[0];
  const float* audio = (const float*)d_in[1];
  const float* lut   = (const float*)d_in[2];
  const float* ph0   = (const float*)d_in[3];
  const float* ph1   = (const float*)d_in[4];
  const float* w_ih  = (const float*)d_in[5];
  const float* w_hh  = (const float*)d_in[6];
  const float* b_ih  = (const float*)d_in[7];
  const float* b_hh  = (const float*)d_in[8];
  const float* w_lin = (const float*)d_in[9];
  const float* b_lin = (const float*)d_in[10];
  const float* w1    = (const float*)d_in[11];
  const float* b1    = (const float*)d_in[12];
  const float* w2    = (const float*)d_in[13];
  const float* b2    = (const float*)d_in[14];
  const float* w3    = (const float*)d_in[15];
  const float* b3    = (const float*)d_in[16];
  const float* modw  = (const float*)d_in[17];
  const float* mr    = (const float*)d_in[18];
  const float* mi    = (const float*)d_in[19];
  const float* fw1   = (const float*)d_in[20];
  const float* fb1   = (const float*)d_in[21];
  const float* fw2   = (const float*)d_in[22];
  const float* fb2   = (const float*)d_in[23];
  const float* fw3   = (const float*)d_in[24];
  const float* fb3   = (const float*)d_in[25];
  float* ws  = (float*)d_ws;
  float* out = (float*)d_out;

  k1_xw_gemm<<<dim3(257), dim3(256), 0, stream>>>(widx, lut, w_ih, b_ih, b_hh, mr, mi, ws);
  k2_lstm<<<dim3(32), dim3(512), 0, stream>>>(w_hh, ws);
  k3_mix<<<dim3(1024), dim3(256), 0, stream>>>(widx, audio, ph0, ph1, w_lin, b_lin,
                                               w1, b1, w2, b2, w3, b3, modw, ws);
  k4_meas<<<dim3(256), dim3(256), 0, stream>>>(ws);
  k5_final<<<dim3(32), dim3(128), 0, stream>>>(fw1, fb1, fw2, fb2, fw3, fb3, ws, out);
}

// Round 3
// 198.262 us; speedup vs baseline: 1.5363x; 1.5363x over previous
//
#include <hip/hip_runtime.h>
#include <math.h>

// ---------------- problem constants ----------------
// B=32, S=32, EMB=300, AUDIO=74, HID=128, D1=D2=16, DIM=256, UNITS=128, CELL=64

// ---------------- workspace layout (float offsets) ----------------
static constexpr unsigned XW0_OFF  = 0u;
static constexpr unsigned XW1_OFF  = 524288u;            // 1024*512
static constexpr unsigned HOUT_OFF = 1048576u;
static constexpr unsigned XMAT_OFF = HOUT_OFF + 131072u; // 1179648
static constexpr unsigned WT_OFF   = XMAT_OFF + 524288u; // 1703936
static constexpr unsigned VPP_OFF  = WT_OFF + 1024u;     // 1704960
static constexpr unsigned PP_OFF   = VPP_OFF + 131072u;  // 1836032
static constexpr unsigned PP_HALF  = 262144u;            // 1024*256

// =====================================================================
// K1: xw[r][j] = sum_k lut[word[r]][k] * w_ih[j][k]  (+ b_ih + b_hh on kq==0)
//     bid <  256 : GEMM 64x64 tiles, 4x4 micro, k split [0,152)/[152,300).
//     bid >= 256 : V'' builder, one block per unit u (128 blocks),
//                  fully coalesced, register-resident (round-2 fix for the
//                  121 us single-block straggler: VALUBusy 2%, occ 1%).
// =====================================================================
__global__ __launch_bounds__(256) void k1_xw_gemm(
    const int* __restrict__ widx, const float* __restrict__ lut,
    const float* __restrict__ w_ih, const float* __restrict__ b_ih,
    const float* __restrict__ b_hh,
    const float* __restrict__ mr, const float* __restrict__ mi,
    float* __restrict__ ws)
{
  const int bid = blockIdx.x;
  const int t = threadIdx.x;

  if (bid >= 256) {
    // ---- V'' rows: 2u = [vr_u | vi_u], 2u+1 = [-vi_u | vr_u], unit-norm
    const int u = bid - 256;                 // 0..127
    float r  = mr[u * 256 + t];
    float ii = mi[u * 256 + t];
    float sq = r * r + ii * ii;
    #pragma unroll
    for (int off = 1; off < 64; off <<= 1) sq += __shfl_xor(sq, off);
    __shared__ float wsum[4];
    if ((t & 63) == 0) wsum[t >> 6] = sq;
    __syncthreads();
    float tot = wsum[0] + wsum[1] + wsum[2] + wsum[3];
    float inv = 1.0f / (sqrtf(tot) + 1e-10f);
    float vr = r * inv, vi = ii * inv;
    float* vpp = ws + VPP_OFF;
    vpp[(2 * u) * 512 + t]           = vr;
    vpp[(2 * u) * 512 + 256 + t]     = vi;
    vpp[(2 * u + 1) * 512 + t]       = -vi;
    vpp[(2 * u + 1) * 512 + 256 + t] = vr;
    return;
  }

  const int rb = bid & 15, cb = (bid >> 4) & 7, kq = bid >> 7;
  const int R = rb * 64, C = cb * 64;
  const int kbase_g = kq * 152;
  const int ktot = kq ? 148 : 152;

  __shared__ alignas(16) float As[32][68];
  __shared__ alignas(16) float Ws[32][68];

  float acc[4][4] = {};
  const int r0 = (t & 15) * 4, j0 = (t >> 4) * 4;

  for (int kt = 0; kt < 5; ++kt) {
    int kl = ktot - kt * 32; if (kl > 32) kl = 32;   // 32,32,32,32,24/20 (all %4==0)
    #pragma unroll
    for (int pass = 0; pass < 2; ++pass) {
      int rr = (t >> 3) + pass * 32;
      int kk4 = (t & 7) * 4;
      float4 av = make_float4(0.f, 0.f, 0.f, 0.f);
      float4 wv = make_float4(0.f, 0.f, 0.f, 0.f);
      if (kk4 < kl) {
        int gk = kbase_g + kt * 32 + kk4;
        int word = widx[R + rr];
        av = *(const float4*)&lut[word * 300 + gk];
        wv = *(const float4*)&w_ih[(C + rr) * 300 + gk];
      }
      As[kk4 + 0][rr] = av.x; As[kk4 + 1][rr] = av.y;
      As[kk4 + 2][rr] = av.z; As[kk4 + 3][rr] = av.w;
      Ws[kk4 + 0][rr] = wv.x; Ws[kk4 + 1][rr] = wv.y;
      Ws[kk4 + 2][rr] = wv.z; Ws[kk4 + 3][rr] = wv.w;
    }
    __syncthreads();
    #pragma unroll
    for (int k = 0; k < 32; ++k) {
      float4 a4 = *(const float4*)&As[k][r0];
      float4 w4 = *(const float4*)&Ws[k][j0];
      float ar[4] = {a4.x, a4.y, a4.z, a4.w};
      float wr[4] = {w4.x, w4.y, w4.z, w4.w};
      #pragma unroll
      for (int i2 = 0; i2 < 4; ++i2)
        #pragma unroll
        for (int j2 = 0; j2 < 4; ++j2)
          acc[i2][j2] = fmaf(ar[i2], wr[j2], acc[i2][j2]);
    }
    __syncthreads();
  }

  float* xw = ws + (kq ? XW1_OFF : XW0_OFF);
  #pragma unroll
  for (int i2 = 0; i2 < 4; ++i2) {
    int row = R + r0 + i2, col = C + j0;
    float4 v = make_float4(acc[i2][0], acc[i2][1], acc[i2][2], acc[i2][3]);
    if (kq == 0) {
      v.x += b_ih[col + 0] + b_hh[col + 0];
      v.y += b_ih[col + 1] + b_hh[col + 1];
      v.z += b_ih[col + 2] + b_hh[col + 2];
      v.w += b_ih[col + 3] + b_hh[col + 3];
    }
    *(float4*)&xw[row * 512 + col] = v;
  }
}

// =====================================================================
// K2: LSTM recurrence. One block per batch element, 512 threads.
//     thread = (jj = gate-unit 0..127, kq = k-quarter 0..3).
//     w_hh weight-stationary in VGPRs; h double-buffered in LDS;
//     shuffle-reduce partials over kq. xw loads issue at step top and are
//     consumed after the FMA chain -> latency hidden within the step.
// =====================================================================
__global__ __launch_bounds__(512, 2) void k2_lstm(
    const float* __restrict__ w_hh, float* __restrict__ ws)
{
  const int b = blockIdx.x;
  const int t = threadIdx.x;
  const int jj = t >> 2;     // 0..127
  const int kq = t & 3;      // 0..3

  float4 wreg[4][8];
  #pragma unroll
  for (int g = 0; g < 4; ++g) {
    const float* wp = w_hh + (jj + 128 * g) * 128 + kq * 32;
    #pragma unroll
    for (int i = 0; i < 8; ++i) wreg[g][i] = *(const float4*)&wp[i * 4];
  }

  __shared__ alignas(16) float hbuf[2][128];
  if (t < 128) hbuf[0][t] = 0.f;

  const float* xw0 = ws + XW0_OFF;
  const float* xw1 = ws + XW1_OFF;
  float* hout = ws + HOUT_OFF;

  float c = 0.f;
  float hhist[32];
  __syncthreads();

  for (int s = 0; s < 32; ++s) {
    const int bs = b * 32 + s;
    float xg0 = 0.f, xg1 = 0.f, xg2 = 0.f, xg3 = 0.f;
    if (kq == 0) {
      int base = bs * 512 + jj;
      xg0 = xw0[base +   0] + xw1[base +   0];
      xg1 = xw0[base + 128] + xw1[base + 128];
      xg2 = xw0[base + 256] + xw1[base + 256];
      xg3 = xw0[base + 384] + xw1[base + 384];
    }
    const float4* hb = (const float4*)hbuf[s & 1] + kq * 8;
    float a0 = 0.f, a1 = 0.f, a2 = 0.f, a3 = 0.f;
    #pragma unroll
    for (int i = 0; i < 8; ++i) {
      float4 h4 = hb[i];
      a0 = fmaf(wreg[0][i].x, h4.x, fmaf(wreg[0][i].y, h4.y, fmaf(wreg[0][i].z, h4.z, fmaf(wreg[0][i].w, h4.w, a0))));
      a1 = fmaf(wreg[1][i].x, h4.x, fmaf(wreg[1][i].y, h4.y, fmaf(wreg[1][i].z, h4.z, fmaf(wreg[1][i].w, h4.w, a1))));
      a2 = fmaf(wreg[2][i].x, h4.x, fmaf(wreg[2][i].y, h4.y, fmaf(wreg[2][i].z, h4.z, fmaf(wreg[2][i].w, h4.w, a2))));
      a3 = fmaf(wreg[3][i].x, h4.x, fmaf(wreg[3][i].y, h4.y, fmaf(wreg[3][i].z, h4.z, fmaf(wreg[3][i].w, h4.w, a3))));
    }
    a0 += __shfl_xor(a0, 1); a0 += __shfl_xor(a0, 2);
    a1 += __shfl_xor(a1, 1); a1 += __shfl_xor(a1, 2);
    a2 += __shfl_xor(a2, 1); a2 += __shfl_xor(a2, 2);
    a3 += __shfl_xor(a3, 1); a3 += __shfl_xor(a3, 2);
    if (kq == 0) {
      float gi = xg0 + a0, gf = xg1 + a1, gg = xg2 + a2, go = xg3 + a3;
      float si = 1.f / (1.f + __expf(-gi));
      float sf = 1.f / (1.f + __expf(-gf));
      float tg = 1.f - 2.f / (1.f + __expf(2.f * gg));
      float so = 1.f / (1.f + __expf(-go));
      c = sf * c + si * tg;
      float tc = 1.f - 2.f / (1.f + __expf(2.f * c));
      float hn = so * tc;
      hbuf[(s + 1) & 1][jj] = hn;
      hhist[s] = hn;
    }
    __syncthreads();
  }
  if (kq == 0) {
    #pragma unroll
    for (int s = 0; s < 32; ++s) hout[(b * 32 + s) * 128 + jj] = hhist[s];
  }
}

// =====================================================================
// K3: per (b,s): amp0 = h@w_lin.T+b_lin; audio MLP -> amp1; norms; phases;
//     tpr/tpi x r1/i1 outer products -> X=[real|imag] row; weight scalar.
// =====================================================================
__global__ __launch_bounds__(256) void k3_mix(
    const int* __restrict__ widx, const float* __restrict__ audio,
    const float* __restrict__ ph0t, const float* __restrict__ ph1t,
    const float* __restrict__ w_lin, const float* __restrict__ b_lin,
    const float* __restrict__ w1, const float* __restrict__ b1,
    const float* __restrict__ w2, const float* __restrict__ b2,
    const float* __restrict__ w3, const float* __restrict__ b3,
    const float* __restrict__ modw, float* __restrict__ ws)
{
  const int bs = blockIdx.x;
  const int t = threadIdx.x;
  __shared__ float amp0[16], a1s[16], a2s[16], amp1[16];
  __shared__ float tpr[16], tpi[16], r1s[16], i1s[16];
  __shared__ float nn[2];

  const float* hrow = ws + HOUT_OFF + bs * 128;
  if (t < 16) {
    float acc = b_lin[t];
    for (int u = 0; u < 128; ++u) acc = fmaf(hrow[u], w_lin[t * 128 + u], acc);
    amp0[t] = acc;
  } else if (t >= 64 && t < 80) {
    int d = t - 64;
    float acc = b1[d];
    for (int k = 0; k < 74; ++k) acc = fmaf(audio[bs * 74 + k], w1[d * 74 + k], acc);
    a1s[d] = fmaxf(acc, 0.f);
  }
  __syncthreads();
  if (t < 16) {
    float acc = b2[t];
    #pragma unroll
    for (int k = 0; k < 16; ++k) acc = fmaf(a1s[k], w2[t * 16 + k], acc);
    a2s[t] = fmaxf(acc, 0.f);
  }
  __syncthreads();
  if (t < 16) {
    float acc = b3[t];
    #pragma unroll
    for (int k = 0; k < 16; ++k) acc = fmaf(a2s[k], w3[t * 16 + k], acc);
    amp1[t] = fmaxf(acc, 0.f);
  }
  __syncthreads();
  if (t == 0) {
    float sq = 0.f;
    #pragma unroll
    for (int d = 0; d < 16; ++d) sq += amp0[d] * amp0[d];
    nn[0] = sqrtf(sq);
  } else if (t == 64) {
    float sq = 0.f;
    #pragma unroll
    for (int d = 0; d < 16; ++d) sq += amp1[d] * amp1[d];
    nn[1] = sqrtf(sq);
  }
  __syncthreads();
  const int word = widx[bs];
  if (t < 16) {
    float k0 = amp0[t] / (nn[0] + 1e-10f);
    float ph = ph0t[word * 16 + t];
    float cc = cosf(ph), ssn = sinf(ph);
    tpr[t] = k0 * (cc - ssn);       // r0 - i0
    tpi[t] = k0 * (cc + ssn);       // r0 + i0
  } else if (t >= 64 && t < 80) {
    int d = t - 64;
    float k1 = amp1[d] / (nn[1] + 1e-10f);
    float ph = ph1t[word * 16 + d];
    r1s[d] = k1 * cosf(ph);
    i1s[d] = k1 * sinf(ph);
  } else if (t == 128) {
    float e0 = __expf(modw[0]), e1 = __expf(modw[1]);
    float mw0 = e0 / (e0 + e1);
    ws[WT_OFF + bs] = mw0 * nn[0] + (1.f - mw0) * nn[1];
  }
  __syncthreads();
  const int i2 = t >> 4, j2 = t & 15;
  float rr = tpr[i2] * r1s[j2] - tpi[i2] * i1s[j2];
  float im = tpr[i2] * i1s[j2] + tpi[i2] * r1s[j2];
  float* X = ws + XMAT_OFF;
  X[bs * 512 + t] = rr;
  X[bs * 512 + 256 + t] = im;
}

// =====================================================================
// K4: P[r][c] = sum_k X[r][k] * V''[c][k]   (1024 x 256, k=512 split x4)
//     writes per-kq partials; 64x64 tiles, 4x4 micro.
// =====================================================================
__global__ __launch_bounds__(256) void k4_meas(float* __restrict__ ws)
{
  const int bid = blockIdx.x, t = threadIdx.x;
  const int rb = bid & 15, cb = (bid >> 4) & 3, kq = bid >> 6;
  const int R = rb * 64, C = cb * 64;
  const float* X = ws + XMAT_OFF;
  const float* V = ws + VPP_OFF;
  __shared__ alignas(16) float Xs[32][68];
  __shared__ alignas(16) float Vs[32][68];
  float acc[4][4] = {};
  const int r0 = (t & 15) * 4, j0 = (t >> 4) * 4;

  for (int kt = 0; kt < 4; ++kt) {
    #pragma unroll
    for (int pass = 0; pass < 2; ++pass) {
      int rr = (t >> 3) + pass * 32;
      int kk4 = (t & 7) * 4;
      int gk = kq * 128 + kt * 32 + kk4;
      float4 xv = *(const float4*)&X[(R + rr) * 512 + gk];
      float4 vv = *(const float4*)&V[(C + rr) * 512 + gk];
      Xs[kk4 + 0][rr] = xv.x; Xs[kk4 + 1][rr] = xv.y;
      Xs[kk4 + 2][rr] = xv.z; Xs[kk4 + 3][rr] = xv.w;
      Vs[kk4 + 0][rr] = vv.x; Vs[kk4 + 1][rr] = vv.y;
      Vs[kk4 + 2][rr] = vv.z; Vs[kk4 + 3][rr] = vv.w;
    }
    __syncthreads();
    #pragma unroll
    for (int k = 0; k < 32; ++k) {
      float4 a4 = *(const float4*)&Xs[k][r0];
      float4 w4 = *(const float4*)&Vs[k][j0];
      float ar[4] = {a4.x, a4.y, a4.z, a4.w};
      float wr[4] = {w4.x, w4.y, w4.z, w4.w};
      #pragma unroll
      for (int i2 = 0; i2 < 4; ++i2)
        #pragma unroll
        for (int j2 = 0; j2 < 4; ++j2)
          acc[i2][j2] = fmaf(ar[i2], wr[j2], acc[i2][j2]);
    }
    __syncthreads();
  }
  float* Pp = ws + PP_OFF + (unsigned)kq * PP_HALF;
  #pragma unroll
  for (int i2 = 0; i2 < 4; ++i2) {
    float4 v = make_float4(acc[i2][0], acc[i2][1], acc[i2][2], acc[i2][3]);
    *(float4*)&Pp[(R + r0 + i2) * 256 + C + j0] = v;
  }
}

// =====================================================================
// K5: per b: p[s][u] = P[2u]^2 + P[2u+1]^2 (sum kq partials);
//     n-gram softmax mixes (n=1,3 zero-padded), max-pool, final MLP.
// =====================================================================
__global__ __launch_bounds__(128) void k5_final(
    const float* __restrict__ fw1, const float* __restrict__ fb1,
    const float* __restrict__ fw2, const float* __restrict__ fb2,
    const float* __restrict__ fw3, const float* __restrict__ fb3,
    const float* __restrict__ ws, float* __restrict__ out)
{
  const int b = blockIdx.x, t = threadIdx.x;
  __shared__ float ewt[34], feat[128], y1[64], y2[64];
  if (t < 32) ewt[t] = expf(ws[WT_OFF + b * 32 + t]);
  if (t == 0) { ewt[32] = 1.f; ewt[33] = 1.f; }
  __syncthreads();

  const float* Pp = ws + PP_OFF;
  float p[32];
  #pragma unroll
  for (int s = 0; s < 32; ++s) {
    int bs = b * 32 + s;
    float A = 0.f, Bv = 0.f;
    #pragma unroll
    for (int kq = 0; kq < 4; ++kq) {
      A  += Pp[kq * PP_HALF + bs * 256 + 2 * t];
      Bv += Pp[kq * PP_HALF + bs * 256 + 2 * t + 1];
    }
    p[s] = A * A + Bv * Bv;
  }
  float m = -1e30f;
  #pragma unroll
  for (int s = 0; s < 32; ++s) m = fmaxf(m, p[s]);        // n=1 (softmax of 1 elem = 1)
  #pragma unroll
  for (int s = 0; s < 32; ++s) {                          // n=3, zero-padded softmax
    float e0 = ewt[s], e1 = ewt[s + 1], e2 = ewt[s + 2];
    float num = e0 * p[s];
    if (s + 1 < 32) num += e1 * p[s + 1];
    if (s + 2 < 32) num += e2 * p[s + 2];
    m = fmaxf(m, num / (e0 + e1 + e2));
  }
  feat[t] = m;
  __syncthreads();
  if (t < 64) {
    float acc = fb1[t];
    for (int k = 0; k < 128; ++k) acc = fmaf(feat[k], fw1[t * 128 + k], acc);
    y1[t] = fmaxf(acc, 0.f);
  }
  __syncthreads();
  if (t < 64) {
    float acc = fb2[t];
    #pragma unroll
    for (int k = 0; k < 64; ++k) acc = fmaf(y1[k], fw2[t * 64 + k], acc);
    y2[t] = fmaxf(acc, 0.f);
  }
  __syncthreads();
  if (t == 0) {
    float acc = fb3[0];
    #pragma unroll
    for (int k = 0; k < 64; ++k) acc = fmaf(y2[k], fw3[k], acc);
    out[b] = acc;
  }
}

// =====================================================================
extern "C" void kernel_launch(void* const* d_in, const int* in_sizes, int n_in,
                              void* d_out, int out_size, void* d_ws, size_t ws_size,
                              hipStream_t stream) {
  const int*   widx  = (const int*)d_in[0];
  const float* audio = (const float*)d_in[1];
  const float* lut   = (const float*)d_in[2];
  const float* ph0   = (const float*)d_in[3];
  const float* ph1   = (const float*)d_in[4];
  const float* w_ih  = (const float*)d_in[5];
  const float* w_hh  = (const float*)d_in[6];
  const float* b_ih  = (const float*)d_in[7];
  const float* b_hh  = (const float*)d_in[8];
  const float* w_lin = (const float*)d_in[9];
  const float* b_lin = (const float*)d_in[10];
  const float* w1    = (const float*)d_in[11];
  const float* b1    = (const float*)d_in[12];
  const float* w2    = (const float*)d_in[13];
  const float* b2    = (const float*)d_in[14];
  const float* w3    = (const float*)d_in[15];
  const float* b3    = (const float*)d_in[16];
  const float* modw  = (const float*)d_in[17];
  const float* mr    = (const float*)d_in[18];
  const float* mi    = (const float*)d_in[19];
  const float* fw1   = (const float*)d_in[20];
  const float* fb1   = (const float*)d_in[21];
  const float* fw2   = (const float*)d_in[22];
  const float* fb2   = (const float*)d_in[23];
  const float* fw3   = (const float*)d_in[24];
  const float* fb3   = (const float*)d_in[25];
  float* ws  = (float*)d_ws;
  float* out = (float*)d_out;

  k1_xw_gemm<<<dim3(384), dim3(256), 0, stream>>>(widx, lut, w_ih, b_ih, b_hh, mr, mi, ws);
  k2_lstm<<<dim3(32), dim3(512), 0, stream>>>(w_hh, ws);
  k3_mix<<<dim3(1024), dim3(256), 0, stream>>>(widx, audio, ph0, ph1, w_lin, b_lin,
                                               w1, b1, w2, b2, w3, b3, modw, ws);
  k4_meas<<<dim3(256), dim3(256), 0, stream>>>(ws);
  k5_final<<<dim3(32), dim3(128), 0, stream>>>(fw1, fb1, fw2, fb2, fw3, fb3, ws, out);
}

// Round 4
// 194.141 us; speedup vs baseline: 1.5689x; 1.0212x over previous
//
#include <hip/hip_runtime.h>
#include <math.h>

// ---------------- problem constants ----------------
// B=32, S=32, EMB=300, AUDIO=74, HID=128, D1=D2=16, DIM=256, UNITS=128, CELL=64

// ---------------- workspace layout (float offsets) ----------------
static constexpr unsigned XW0_OFF  = 0u;
static constexpr unsigned XW1_OFF  = 524288u;            // 1024*512
static constexpr unsigned HOUT_OFF = 1048576u;
static constexpr unsigned XMAT_OFF = HOUT_OFF + 131072u; // 1179648
static constexpr unsigned WT_OFF   = XMAT_OFF + 524288u; // 1703936
static constexpr unsigned VPP_OFF  = WT_OFF + 1024u;     // 1704960
static constexpr unsigned PP_OFF   = VPP_OFF + 131072u;  // 1836032
static constexpr unsigned PP_HALF  = 262144u;            // 1024*256

// =====================================================================
// K1: xw[r][j] = sum_k lut[word[r]][k] * w_ih[j][k]  (+ b_ih + b_hh on kq==0)
//     bid <  256 : GEMM 64x64 tiles, 4x4 micro, k split [0,152)/[152,300).
//     bid >= 256 : V'' builder, one block per unit u (128 blocks).
// =====================================================================
__global__ __launch_bounds__(256) void k1_xw_gemm(
    const int* __restrict__ widx, const float* __restrict__ lut,
    const float* __restrict__ w_ih, const float* __restrict__ b_ih,
    const float* __restrict__ b_hh,
    const float* __restrict__ mr, const float* __restrict__ mi,
    float* __restrict__ ws)
{
  const int bid = blockIdx.x;
  const int t = threadIdx.x;

  if (bid >= 256) {
    // ---- V'' rows: 2u = [vr_u | vi_u], 2u+1 = [-vi_u | vr_u], unit-norm
    const int u = bid - 256;                 // 0..127
    float r  = mr[u * 256 + t];
    float ii = mi[u * 256 + t];
    float sq = r * r + ii * ii;
    #pragma unroll
    for (int off = 1; off < 64; off <<= 1) sq += __shfl_xor(sq, off);
    __shared__ float wsum[4];
    if ((t & 63) == 0) wsum[t >> 6] = sq;
    __syncthreads();
    float tot = wsum[0] + wsum[1] + wsum[2] + wsum[3];
    float inv = 1.0f / (sqrtf(tot) + 1e-10f);
    float vr = r * inv, vi = ii * inv;
    float* vpp = ws + VPP_OFF;
    vpp[(2 * u) * 512 + t]           = vr;
    vpp[(2 * u) * 512 + 256 + t]     = vi;
    vpp[(2 * u + 1) * 512 + t]       = -vi;
    vpp[(2 * u + 1) * 512 + 256 + t] = vr;
    return;
  }

  const int rb = bid & 15, cb = (bid >> 4) & 7, kq = bid >> 7;
  const int R = rb * 64, C = cb * 64;
  const int kbase_g = kq * 152;
  const int ktot = kq ? 148 : 152;

  __shared__ alignas(16) float As[32][68];
  __shared__ alignas(16) float Ws[32][68];

  float acc[4][4] = {};
  const int r0 = (t & 15) * 4, j0 = (t >> 4) * 4;

  for (int kt = 0; kt < 5; ++kt) {
    int kl = ktot - kt * 32; if (kl > 32) kl = 32;   // 32,32,32,32,24/20
    #pragma unroll
    for (int pass = 0; pass < 2; ++pass) {
      int rr = (t >> 3) + pass * 32;
      int kk4 = (t & 7) * 4;
      float4 av = make_float4(0.f, 0.f, 0.f, 0.f);
      float4 wv = make_float4(0.f, 0.f, 0.f, 0.f);
      if (kk4 < kl) {
        int gk = kbase_g + kt * 32 + kk4;
        int word = widx[R + rr];
        av = *(const float4*)&lut[word * 300 + gk];
        wv = *(const float4*)&w_ih[(C + rr) * 300 + gk];
      }
      As[kk4 + 0][rr] = av.x; As[kk4 + 1][rr] = av.y;
      As[kk4 + 2][rr] = av.z; As[kk4 + 3][rr] = av.w;
      Ws[kk4 + 0][rr] = wv.x; Ws[kk4 + 1][rr] = wv.y;
      Ws[kk4 + 2][rr] = wv.z; Ws[kk4 + 3][rr] = wv.w;
    }
    __syncthreads();
    #pragma unroll
    for (int k = 0; k < 32; ++k) {
      float4 a4 = *(const float4*)&As[k][r0];
      float4 w4 = *(const float4*)&Ws[k][j0];
      float ar[4] = {a4.x, a4.y, a4.z, a4.w};
      float wr[4] = {w4.x, w4.y, w4.z, w4.w};
      #pragma unroll
      for (int i2 = 0; i2 < 4; ++i2)
        #pragma unroll
        for (int j2 = 0; j2 < 4; ++j2)
          acc[i2][j2] = fmaf(ar[i2], wr[j2], acc[i2][j2]);
    }
    __syncthreads();
  }

  float* xw = ws + (kq ? XW1_OFF : XW0_OFF);
  #pragma unroll
  for (int i2 = 0; i2 < 4; ++i2) {
    int row = R + r0 + i2, col = C + j0;
    float4 v = make_float4(acc[i2][0], acc[i2][1], acc[i2][2], acc[i2][3]);
    if (kq == 0) {
      v.x += b_ih[col + 0] + b_hh[col + 0];
      v.y += b_ih[col + 1] + b_hh[col + 1];
      v.z += b_ih[col + 2] + b_hh[col + 2];
      v.w += b_ih[col + 3] + b_hh[col + 3];
    }
    *(float4*)&xw[row * 512 + col] = v;
  }
}

// =====================================================================
// K2: LSTM recurrence. One block per batch element, 1024 threads.
//     thread = (jj = unit 0..127, ko = k-sixteenth 0..7).
//     Per-thread: 4 gates x 16 k = 64 weight VGPRs (round-3 fix: the 512-thr
//     version needed 128 wt regs; compiler capped at VGPR=96 and re-loaded
//     w_hh from L2 every step -> 47.6 us). xg fully preloaded (16 regs,
//     lane owns gate ko&3 / step-half ko>>2) so the step loop is pure
//     LDS+VALU+shuffle. hout stored per step (no hhist). Butterfly reduce
//     over ko via shfl_xor 1/2/4. LDS h reads bank-staggered by ko.
// =====================================================================
__global__ __launch_bounds__(1024, 4) void k2_lstm(
    const float* __restrict__ w_hh, float* __restrict__ ws)
{
  const int b = blockIdx.x;
  const int t = threadIdx.x;
  const int jj = t >> 3;        // 0..127
  const int ko = t & 7;         // 0..7
  const int gstar = ko & 3;     // gate whose xg this lane carries
  const int shalf = ko >> 2;    // step-half whose xg this lane carries
  const int rot = (ko >> 1) & 3;// LDS bank-stagger rotation

  // weights: wreg[g][cc] = w_hh[g*128+jj][ko*16 + ((cc+rot)&3)*4 .. +4)
  float4 wreg[4][4];
  #pragma unroll
  for (int g = 0; g < 4; ++g) {
    const float* wp = w_hh + (g * 128 + jj) * 128 + ko * 16;
    #pragma unroll
    for (int cc = 0; cc < 4; ++cc) {
      int ci = (cc + rot) & 3;
      wreg[g][cc] = *(const float4*)&wp[ci * 4];
    }
  }

  // xg preload: gate gstar, steps shalf*16 + i
  const float* xw0 = ws + XW0_OFF;
  const float* xw1 = ws + XW1_OFF;
  float xg[16];
  {
    const int base = (b * 32 + shalf * 16) * 512 + gstar * 128 + jj;
    #pragma unroll
    for (int i = 0; i < 16; ++i)
      xg[i] = xw0[base + i * 512] + xw1[base + i * 512];
  }
  const float m0 = (gstar == 0) ? 1.f : 0.f;
  const float m1 = (gstar == 1) ? 1.f : 0.f;
  const float m2 = (gstar == 2) ? 1.f : 0.f;
  const float m3 = (gstar == 3) ? 1.f : 0.f;

  __shared__ alignas(16) float hbuf[2][128];
  if (t < 128) hbuf[0][t] = 0.f;
  float* hout = ws + HOUT_OFF;
  float c = 0.f;
  __syncthreads();

  #pragma unroll
  for (int s = 0; s < 32; ++s) {
    const float* hb = hbuf[s & 1] + ko * 16;
    float a0 = 0.f, a1 = 0.f, a2 = 0.f, a3 = 0.f;
    #pragma unroll
    for (int cc = 0; cc < 4; ++cc) {
      int ci = (cc + rot) & 3;                 // address-side rotation only
      float4 h4 = *(const float4*)&hb[ci * 4];
      a0 = fmaf(wreg[0][cc].x, h4.x, fmaf(wreg[0][cc].y, h4.y, fmaf(wreg[0][cc].z, h4.z, fmaf(wreg[0][cc].w, h4.w, a0))));
      a1 = fmaf(wreg[1][cc].x, h4.x, fmaf(wreg[1][cc].y, h4.y, fmaf(wreg[1][cc].z, h4.z, fmaf(wreg[1][cc].w, h4.w, a1))));
      a2 = fmaf(wreg[2][cc].x, h4.x, fmaf(wreg[2][cc].y, h4.y, fmaf(wreg[2][cc].z, h4.z, fmaf(wreg[2][cc].w, h4.w, a2))));
      a3 = fmaf(wreg[3][cc].x, h4.x, fmaf(wreg[3][cc].y, h4.y, fmaf(wreg[3][cc].z, h4.z, fmaf(wreg[3][cc].w, h4.w, a3))));
    }
    // inject x-path gate term (lane owns gate gstar for its step-half)
    {
      float xv = ((s >> 4) == shalf) ? xg[s & 15] : 0.f;
      a0 = fmaf(xv, m0, a0);
      a1 = fmaf(xv, m1, a1);
      a2 = fmaf(xv, m2, a2);
      a3 = fmaf(xv, m3, a3);
    }
    // butterfly-reduce over ko (8 lanes)
    a0 += __shfl_xor(a0, 1); a0 += __shfl_xor(a0, 2); a0 += __shfl_xor(a0, 4);
    a1 += __shfl_xor(a1, 1); a1 += __shfl_xor(a1, 2); a1 += __shfl_xor(a1, 4);
    a2 += __shfl_xor(a2, 1); a2 += __shfl_xor(a2, 2); a2 += __shfl_xor(a2, 4);
    a3 += __shfl_xor(a3, 1); a3 += __shfl_xor(a3, 2); a3 += __shfl_xor(a3, 4);
    // nonlinearity (all lanes redundantly; identical values -> c stays coherent)
    float si = 1.f / (1.f + __expf(-a0));
    float sf = 1.f / (1.f + __expf(-a1));
    float tg = 1.f - 2.f / (1.f + __expf(2.f * a2));
    float so = 1.f / (1.f + __expf(-a3));
    c = sf * c + si * tg;
    float tc = 1.f - 2.f / (1.f + __expf(2.f * c));
    float hn = so * tc;
    if (ko == 0) {
      hbuf[(s + 1) & 1][jj] = hn;
      hout[(b * 32 + s) * 128 + jj] = hn;
    }
    __syncthreads();
  }
}

// =====================================================================
// K3: per (b,s): amp0 = h@w_lin.T+b_lin; audio MLP -> amp1; norms; phases;
//     tpr/tpi x r1/i1 outer products -> X=[real|imag] row; weight scalar.
// =====================================================================
__global__ __launch_bounds__(256) void k3_mix(
    const int* __restrict__ widx, const float* __restrict__ audio,
    const float* __restrict__ ph0t, const float* __restrict__ ph1t,
    const float* __restrict__ w_lin, const float* __restrict__ b_lin,
    const float* __restrict__ w1, const float* __restrict__ b1,
    const float* __restrict__ w2, const float* __restrict__ b2,
    const float* __restrict__ w3, const float* __restrict__ b3,
    const float* __restrict__ modw, float* __restrict__ ws)
{
  const int bs = blockIdx.x;
  const int t = threadIdx.x;
  __shared__ float amp0[16], a1s[16], a2s[16], amp1[16];
  __shared__ float tpr[16], tpi[16], r1s[16], i1s[16];
  __shared__ float nn[2];

  const float* hrow = ws + HOUT_OFF + bs * 128;
  if (t < 16) {
    float acc = b_lin[t];
    for (int u = 0; u < 128; ++u) acc = fmaf(hrow[u], w_lin[t * 128 + u], acc);
    amp0[t] = acc;
  } else if (t >= 64 && t < 80) {
    int d = t - 64;
    float acc = b1[d];
    for (int k = 0; k < 74; ++k) acc = fmaf(audio[bs * 74 + k], w1[d * 74 + k], acc);
    a1s[d] = fmaxf(acc, 0.f);
  }
  __syncthreads();
  if (t < 16) {
    float acc = b2[t];
    #pragma unroll
    for (int k = 0; k < 16; ++k) acc = fmaf(a1s[k], w2[t * 16 + k], acc);
    a2s[t] = fmaxf(acc, 0.f);
  }
  __syncthreads();
  if (t < 16) {
    float acc = b3[t];
    #pragma unroll
    for (int k = 0; k < 16; ++k) acc = fmaf(a2s[k], w3[t * 16 + k], acc);
    amp1[t] = fmaxf(acc, 0.f);
  }
  __syncthreads();
  if (t == 0) {
    float sq = 0.f;
    #pragma unroll
    for (int d = 0; d < 16; ++d) sq += amp0[d] * amp0[d];
    nn[0] = sqrtf(sq);
  } else if (t == 64) {
    float sq = 0.f;
    #pragma unroll
    for (int d = 0; d < 16; ++d) sq += amp1[d] * amp1[d];
    nn[1] = sqrtf(sq);
  }
  __syncthreads();
  const int word = widx[bs];
  if (t < 16) {
    float k0 = amp0[t] / (nn[0] + 1e-10f);
    float ph = ph0t[word * 16 + t];
    float cc = cosf(ph), ssn = sinf(ph);
    tpr[t] = k0 * (cc - ssn);       // r0 - i0
    tpi[t] = k0 * (cc + ssn);       // r0 + i0
  } else if (t >= 64 && t < 80) {
    int d = t - 64;
    float k1 = amp1[d] / (nn[1] + 1e-10f);
    float ph = ph1t[word * 16 + d];
    r1s[d] = k1 * cosf(ph);
    i1s[d] = k1 * sinf(ph);
  } else if (t == 128) {
    float e0 = __expf(modw[0]), e1 = __expf(modw[1]);
    float mw0 = e0 / (e0 + e1);
    ws[WT_OFF + bs] = mw0 * nn[0] + (1.f - mw0) * nn[1];
  }
  __syncthreads();
  const int i2 = t >> 4, j2 = t & 15;
  float rr = tpr[i2] * r1s[j2] - tpi[i2] * i1s[j2];
  float im = tpr[i2] * i1s[j2] + tpi[i2] * r1s[j2];
  float* X = ws + XMAT_OFF;
  X[bs * 512 + t] = rr;
  X[bs * 512 + 256 + t] = im;
}

// =====================================================================
// K4: P[r][c] = sum_k X[r][k] * V''[c][k]   (1024 x 256, k=512 split x4)
//     writes per-kq partials; 64x64 tiles, 4x4 micro.
// =====================================================================
__global__ __launch_bounds__(256) void k4_meas(float* __restrict__ ws)
{
  const int bid = blockIdx.x, t = threadIdx.x;
  const int rb = bid & 15, cb = (bid >> 4) & 3, kq = bid >> 6;
  const int R = rb * 64, C = cb * 64;
  const float* X = ws + XMAT_OFF;
  const float* V = ws + VPP_OFF;
  __shared__ alignas(16) float Xs[32][68];
  __shared__ alignas(16) float Vs[32][68];
  float acc[4][4] = {};
  const int r0 = (t & 15) * 4, j0 = (t >> 4) * 4;

  for (int kt = 0; kt < 4; ++kt) {
    #pragma unroll
    for (int pass = 0; pass < 2; ++pass) {
      int rr = (t >> 3) + pass * 32;
      int kk4 = (t & 7) * 4;
      int gk = kq * 128 + kt * 32 + kk4;
      float4 xv = *(const float4*)&X[(R + rr) * 512 + gk];
      float4 vv = *(const float4*)&V[(C + rr) * 512 + gk];
      Xs[kk4 + 0][rr] = xv.x; Xs[kk4 + 1][rr] = xv.y;
      Xs[kk4 + 2][rr] = xv.z; Xs[kk4 + 3][rr] = xv.w;
      Vs[kk4 + 0][rr] = vv.x; Vs[kk4 + 1][rr] = vv.y;
      Vs[kk4 + 2][rr] = vv.z; Vs[kk4 + 3][rr] = vv.w;
    }
    __syncthreads();
    #pragma unroll
    for (int k = 0; k < 32; ++k) {
      float4 a4 = *(const float4*)&Xs[k][r0];
      float4 w4 = *(const float4*)&Vs[k][j0];
      float ar[4] = {a4.x, a4.y, a4.z, a4.w};
      float wr[4] = {w4.x, w4.y, w4.z, w4.w};
      #pragma unroll
      for (int i2 = 0; i2 < 4; ++i2)
        #pragma unroll
        for (int j2 = 0; j2 < 4; ++j2)
          acc[i2][j2] = fmaf(ar[i2], wr[j2], acc[i2][j2]);
    }
    __syncthreads();
  }
  float* Pp = ws + PP_OFF + (unsigned)kq * PP_HALF;
  #pragma unroll
  for (int i2 = 0; i2 < 4; ++i2) {
    float4 v = make_float4(acc[i2][0], acc[i2][1], acc[i2][2], acc[i2][3]);
    *(float4*)&Pp[(R + r0 + i2) * 256 + C + j0] = v;
  }
}

// =====================================================================
// K5: per b: p[s][u] = P[2u]^2 + P[2u+1]^2 (sum kq partials);
//     n-gram softmax mixes (n=1,3 zero-padded), max-pool, final MLP.
//     512 threads: (u = t&127, sg = t>>7) -> 8 s per thread; p staged in
//     LDS so n=3 windows cross sg boundaries; 4x fewer loads/thread than
//     the 128-thread version.
// =====================================================================
__global__ __launch_bounds__(512) void k5_final(
    const float* __restrict__ fw1, const float* __restrict__ fb1,
    const float* __restrict__ fw2, const float* __restrict__ fb2,
    const float* __restrict__ fw3, const float* __restrict__ fb3,
    const float* __restrict__ ws, float* __restrict__ out)
{
  const int b = blockIdx.x, t = threadIdx.x;
  const int u = t & 127, sg = t >> 7;      // sg 0..3
  __shared__ float ewt[34];
  __shared__ float pl[32][128];
  __shared__ float fred[4][128];
  __shared__ float feat[128], y1[64], y2[64];
  if (t < 32) ewt[t] = __expf(ws[WT_OFF + b * 32 + t]);
  if (t >= 32 && t < 34) ewt[t] = 1.f;
  __syncthreads();

  const float* Pp = ws + PP_OFF;
  #pragma unroll
  for (int i = 0; i < 8; ++i) {
    int s = sg * 8 + i;
    int bs = b * 32 + s;
    float A = 0.f, Bv = 0.f;
    #pragma unroll
    for (int kq = 0; kq < 4; ++kq) {
      A  += Pp[kq * PP_HALF + bs * 256 + 2 * u];
      Bv += Pp[kq * PP_HALF + bs * 256 + 2 * u + 1];
    }
    pl[s][u] = A * A + Bv * Bv;
  }
  __syncthreads();

  float m = -1e30f;
  #pragma unroll
  for (int i = 0; i < 8; ++i) {
    int s = sg * 8 + i;
    float p0 = pl[s][u];
    m = fmaxf(m, p0);                       // n=1 (softmax of 1 elem = 1)
    float e0 = ewt[s], e1 = ewt[s + 1], e2 = ewt[s + 2];
    float num = e0 * p0;
    if (s + 1 < 32) num += e1 * pl[s + 1][u];
    if (s + 2 < 32) num += e2 * pl[s + 2][u];
    m = fmaxf(m, num / (e0 + e1 + e2));
  }
  fred[sg][u] = m;
  __syncthreads();
  if (t < 128)
    feat[t] = fmaxf(fmaxf(fred[0][t], fred[1][t]), fmaxf(fred[2][t], fred[3][t]));
  __syncthreads();
  if (t < 64) {
    float acc = fb1[t];
    for (int k = 0; k < 128; ++k) acc = fmaf(feat[k], fw1[t * 128 + k], acc);
    y1[t] = fmaxf(acc, 0.f);
  }
  __syncthreads();
  if (t < 64) {
    float acc = fb2[t];
    #pragma unroll
    for (int k = 0; k < 64; ++k) acc = fmaf(y1[k], fw2[t * 64 + k], acc);
    y2[t] = fmaxf(acc, 0.f);
  }
  __syncthreads();
  if (t == 0) {
    float acc = fb3[0];
    #pragma unroll
    for (int k = 0; k < 64; ++k) acc = fmaf(y2[k], fw3[k], acc);
    out[b] = acc;
  }
}

// =====================================================================
extern "C" void kernel_launch(void* const* d_in, const int* in_sizes, int n_in,
                              void* d_out, int out_size, void* d_ws, size_t ws_size,
                              hipStream_t stream) {
  const int*   widx  = (const int*)d_in[0];
  const float* audio = (const float*)d_in[1];
  const float* lut   = (const float*)d_in[2];
  const float* ph0   = (const float*)d_in[3];
  const float* ph1   = (const float*)d_in[4];
  const float* w_ih  = (const float*)d_in[5];
  const float* w_hh  = (const float*)d_in[6];
  const float* b_ih  = (const float*)d_in[7];
  const float* b_hh  = (const float*)d_in[8];
  const float* w_lin = (const float*)d_in[9];
  const float* b_lin = (const float*)d_in[10];
  const float* w1    = (const float*)d_in[11];
  const float* b1    = (const float*)d_in[12];
  const float* w2    = (const float*)d_in[13];
  const float* b2    = (const float*)d_in[14];
  const float* w3    = (const float*)d_in[15];
  const float* b3    = (const float*)d_in[16];
  const float* modw  = (const float*)d_in[17];
  const float* mr    = (const float*)d_in[18];
  const float* mi    = (const float*)d_in[19];
  const float* fw1   = (const float*)d_in[20];
  const float* fb1   = (const float*)d_in[21];
  const float* fw2   = (const float*)d_in[22];
  const float* fb2   = (const float*)d_in[23];
  const float* fw3   = (const float*)d_in[24];
  const float* fb3   = (const float*)d_in[25];
  float* ws  = (float*)d_ws;
  float* out = (float*)d_out;

  k1_xw_gemm<<<dim3(384), dim3(256), 0, stream>>>(widx, lut, w_ih, b_ih, b_hh, mr, mi, ws);
  k2_lstm<<<dim3(32), dim3(1024), 0, stream>>>(w_hh, ws);
  k3_mix<<<dim3(1024), dim3(256), 0, stream>>>(widx, audio, ph0, ph1, w_lin, b_lin,
                                               w1, b1, w2, b2, w3, b3, modw, ws);
  k4_meas<<<dim3(256), dim3(256), 0, stream>>>(ws);
  k5_final<<<dim3(32), dim3(512), 0, stream>>>(fw1, fb1, fw2, fb2, fw3, fb3, ws, out);
}

// Round 5
// 181.912 us; speedup vs baseline: 1.6744x; 1.0672x over previous
//
#include <hip/hip_runtime.h>
#include <math.h>

// ---------------- problem constants ----------------
// B=32, S=32, EMB=300, AUDIO=74, HID=128, D1=D2=16, DIM=256, UNITS=128, CELL=64

// ---------------- workspace layout (float offsets) ----------------
static constexpr unsigned XW0_OFF  = 0u;
static constexpr unsigned XW1_OFF  = 524288u;            // 1024*512
static constexpr unsigned HOUT_OFF = 1048576u;
static constexpr unsigned XMAT_OFF = HOUT_OFF + 131072u; // 1179648
static constexpr unsigned WT_OFF   = XMAT_OFF + 524288u; // 1703936
static constexpr unsigned VPP_OFF  = WT_OFF + 1024u;     // 1704960
static constexpr unsigned PP_OFF   = VPP_OFF + 131072u;  // 1836032
static constexpr unsigned PP_HALF  = 262144u;            // 1024*256

// =====================================================================
// K1: xw[r][j] = sum_k lut[word[r]][k] * w_ih[j][k]  (+ b_ih + b_hh on kq==0)
//     bid <  256 : GEMM 64x64 tiles, 4x4 micro, k split [0,152)/[152,300).
//     bid >= 256 : V'' builder, one block per unit u (128 blocks).
// =====================================================================
__global__ __launch_bounds__(256) void k1_xw_gemm(
    const int* __restrict__ widx, const float* __restrict__ lut,
    const float* __restrict__ w_ih, const float* __restrict__ b_ih,
    const float* __restrict__ b_hh,
    const float* __restrict__ mr, const float* __restrict__ mi,
    float* __restrict__ ws)
{
  const int bid = blockIdx.x;
  const int t = threadIdx.x;

  if (bid >= 256) {
    // ---- V'' rows: 2u = [vr_u | vi_u], 2u+1 = [-vi_u | vr_u], unit-norm
    const int u = bid - 256;                 // 0..127
    float r  = mr[u * 256 + t];
    float ii = mi[u * 256 + t];
    float sq = r * r + ii * ii;
    #pragma unroll
    for (int off = 1; off < 64; off <<= 1) sq += __shfl_xor(sq, off);
    __shared__ float wsum[4];
    if ((t & 63) == 0) wsum[t >> 6] = sq;
    __syncthreads();
    float tot = wsum[0] + wsum[1] + wsum[2] + wsum[3];
    float inv = 1.0f / (sqrtf(tot) + 1e-10f);
    float vr = r * inv, vi = ii * inv;
    float* vpp = ws + VPP_OFF;
    vpp[(2 * u) * 512 + t]           = vr;
    vpp[(2 * u) * 512 + 256 + t]     = vi;
    vpp[(2 * u + 1) * 512 + t]       = -vi;
    vpp[(2 * u + 1) * 512 + 256 + t] = vr;
    return;
  }

  const int rb = bid & 15, cb = (bid >> 4) & 7, kq = bid >> 7;
  const int R = rb * 64, C = cb * 64;
  const int kbase_g = kq * 152;
  const int ktot = kq ? 148 : 152;

  __shared__ alignas(16) float As[32][68];
  __shared__ alignas(16) float Ws[32][68];

  float acc[4][4] = {};
  const int r0 = (t & 15) * 4, j0 = (t >> 4) * 4;

  for (int kt = 0; kt < 5; ++kt) {
    int kl = ktot - kt * 32; if (kl > 32) kl = 32;   // 32,32,32,32,24/20
    #pragma unroll
    for (int pass = 0; pass < 2; ++pass) {
      int rr = (t >> 3) + pass * 32;
      int kk4 = (t & 7) * 4;
      float4 av = make_float4(0.f, 0.f, 0.f, 0.f);
      float4 wv = make_float4(0.f, 0.f, 0.f, 0.f);
      if (kk4 < kl) {
        int gk = kbase_g + kt * 32 + kk4;
        int word = widx[R + rr];
        av = *(const float4*)&lut[word * 300 + gk];
        wv = *(const float4*)&w_ih[(C + rr) * 300 + gk];
      }
      As[kk4 + 0][rr] = av.x; As[kk4 + 1][rr] = av.y;
      As[kk4 + 2][rr] = av.z; As[kk4 + 3][rr] = av.w;
      Ws[kk4 + 0][rr] = wv.x; Ws[kk4 + 1][rr] = wv.y;
      Ws[kk4 + 2][rr] = wv.z; Ws[kk4 + 3][rr] = wv.w;
    }
    __syncthreads();
    #pragma unroll
    for (int k = 0; k < 32; ++k) {
      float4 a4 = *(const float4*)&As[k][r0];
      float4 w4 = *(const float4*)&Ws[k][j0];
      float ar[4] = {a4.x, a4.y, a4.z, a4.w};
      float wr[4] = {w4.x, w4.y, w4.z, w4.w};
      #pragma unroll
      for (int i2 = 0; i2 < 4; ++i2)
        #pragma unroll
        for (int j2 = 0; j2 < 4; ++j2)
          acc[i2][j2] = fmaf(ar[i2], wr[j2], acc[i2][j2]);
    }
    __syncthreads();
  }

  float* xw = ws + (kq ? XW1_OFF : XW0_OFF);
  #pragma unroll
  for (int i2 = 0; i2 < 4; ++i2) {
    int row = R + r0 + i2, col = C + j0;
    float4 v = make_float4(acc[i2][0], acc[i2][1], acc[i2][2], acc[i2][3]);
    if (kq == 0) {
      v.x += b_ih[col + 0] + b_hh[col + 0];
      v.y += b_ih[col + 1] + b_hh[col + 1];
      v.z += b_ih[col + 2] + b_hh[col + 2];
      v.w += b_ih[col + 3] + b_hh[col + 3];
    }
    *(float4*)&xw[row * 512 + col] = v;
  }
}

// =====================================================================
// K2: LSTM recurrence — producer/consumer wave specialization.
//     Round-4 analysis: 47.5us = DS-pipe bound (__shfl = ds_bpermute on
//     CDNA; 12/thread x 16 waves ~1400 cyc/step) + 16x-redundant exp.
//     New design: 640 threads = 8 compute waves + 2 reducer waves.
//       compute wave wv (k-slice 16): lane l owns units {l, 64+l} x 4
//       gates, 128 weight VGPRs pinned via asm; reads h (broadcast b128),
//       writes 8 partials as 2x ds_write_b128 (contiguous, 0 conflicts).
//       reducer lane owns unit jj: 8x b128 partial reads + xw inject +
//       5 exp + c/h update. Zero shuffles; exp count cut 8x.
//     Both branches execute 1 + 2*32 barriers in lockstep (AMD s_barrier
//     counts waves) — standard producer/consumer pattern.
// =====================================================================
__global__ __launch_bounds__(640, 1) void k2_lstm(
    const float* __restrict__ w_hh, float* __restrict__ ws)
{
  const int b = blockIdx.x;
  const int t = threadIdx.x;
  const int wv = t >> 6;      // wave 0..9
  const int l  = t & 63;

  __shared__ alignas(16) float part[8][512];
  __shared__ alignas(16) float hbuf[2][128];

  float* hout = ws + HOUT_OFF;
  const float* xw0 = ws + XW0_OFF;
  const float* xw1 = ws + XW1_OFF;

  if (t < 128) hbuf[0][t] = 0.f;

  if (wv < 8) {
    // ---------------- compute waves ----------------
    float4 wA[4][4], wB[4][4];
    #pragma unroll
    for (int g = 0; g < 4; ++g) {
      const float* pA = w_hh + (g * 128 + l) * 128 + wv * 16;
      const float* pB = w_hh + (g * 128 + 64 + l) * 128 + wv * 16;
      #pragma unroll
      for (int c = 0; c < 4; ++c) {
        wA[g][c] = *(const float4*)&pA[c * 4];
        wB[g][c] = *(const float4*)&pB[c * 4];
      }
    }
    // pin weights into VGPRs (compiler sank these loads in rounds 2-3)
    #pragma unroll
    for (int g = 0; g < 4; ++g)
      #pragma unroll
      for (int c = 0; c < 4; ++c) {
        asm volatile("" : "+v"(wA[g][c].x), "+v"(wA[g][c].y), "+v"(wA[g][c].z), "+v"(wA[g][c].w));
        asm volatile("" : "+v"(wB[g][c].x), "+v"(wB[g][c].y), "+v"(wB[g][c].z), "+v"(wB[g][c].w));
      }
    __syncthreads();                       // hbuf[0] ready
    const float* hbase = &hbuf[0][0];
    for (int s = 0; s < 32; ++s) {
      const float* hb = hbase + (s & 1) * 128 + wv * 16;
      float aA0 = 0.f, aA1 = 0.f, aA2 = 0.f, aA3 = 0.f;
      float aB0 = 0.f, aB1 = 0.f, aB2 = 0.f, aB3 = 0.f;
      #pragma unroll
      for (int c = 0; c < 4; ++c) {
        float4 h4 = *(const float4*)&hb[c * 4];
        aA0 = fmaf(wA[0][c].x, h4.x, fmaf(wA[0][c].y, h4.y, fmaf(wA[0][c].z, h4.z, fmaf(wA[0][c].w, h4.w, aA0))));
        aA1 = fmaf(wA[1][c].x, h4.x, fmaf(wA[1][c].y, h4.y, fmaf(wA[1][c].z, h4.z, fmaf(wA[1][c].w, h4.w, aA1))));
        aA2 = fmaf(wA[2][c].x, h4.x, fmaf(wA[2][c].y, h4.y, fmaf(wA[2][c].z, h4.z, fmaf(wA[2][c].w, h4.w, aA2))));
        aA3 = fmaf(wA[3][c].x, h4.x, fmaf(wA[3][c].y, h4.y, fmaf(wA[3][c].z, h4.z, fmaf(wA[3][c].w, h4.w, aA3))));
        aB0 = fmaf(wB[0][c].x, h4.x, fmaf(wB[0][c].y, h4.y, fmaf(wB[0][c].z, h4.z, fmaf(wB[0][c].w, h4.w, aB0))));
        aB1 = fmaf(wB[1][c].x, h4.x, fmaf(wB[1][c].y, h4.y, fmaf(wB[1][c].z, h4.z, fmaf(wB[1][c].w, h4.w, aB1))));
        aB2 = fmaf(wB[2][c].x, h4.x, fmaf(wB[2][c].y, h4.y, fmaf(wB[2][c].z, h4.z, fmaf(wB[2][c].w, h4.w, aB2))));
        aB3 = fmaf(wB[3][c].x, h4.x, fmaf(wB[3][c].y, h4.y, fmaf(wB[3][c].z, h4.z, fmaf(wB[3][c].w, h4.w, aB3))));
      }
      *(float4*)&part[wv][l * 4]       = make_float4(aA0, aA1, aA2, aA3);
      *(float4*)&part[wv][256 + l * 4] = make_float4(aB0, aB1, aB2, aB3);
      __syncthreads();                   // partials ready
      __syncthreads();                   // h(s+1) ready
    }
  } else {
    // ---------------- reducer waves ----------------
    const int jj = (wv - 8) * 64 + l;    // unit 0..127
    float c = 0.f;
    __syncthreads();                     // hbuf[0] ready
    for (int s = 0; s < 32; ++s) {
      // issue xw loads now — hidden under the compute waves' FMA phase
      const int base = (b * 32 + s) * 512 + jj;
      float x0 = xw0[base +   0] + xw1[base +   0];
      float x1 = xw0[base + 128] + xw1[base + 128];
      float x2 = xw0[base + 256] + xw1[base + 256];
      float x3 = xw0[base + 384] + xw1[base + 384];
      __syncthreads();                   // partials ready
      float g0 = x0, g1 = x1, g2 = x2, g3 = x3;
      #pragma unroll
      for (int w = 0; w < 8; ++w) {
        float4 p = *(const float4*)&part[w][jj * 4];
        g0 += p.x; g1 += p.y; g2 += p.z; g3 += p.w;
      }
      float si = 1.f / (1.f + __expf(-g0));
      float sf = 1.f / (1.f + __expf(-g1));
      float tg = 1.f - 2.f / (1.f + __expf(2.f * g2));
      float so = 1.f / (1.f + __expf(-g3));
      c = sf * c + si * tg;
      float tc = 1.f - 2.f / (1.f + __expf(2.f * c));
      float hn = so * tc;
      hbuf[(s + 1) & 1][jj] = hn;
      hout[(b * 32 + s) * 128 + jj] = hn;
      __syncthreads();                   // h(s+1) ready
    }
  }
}

// =====================================================================
// K3: per (b,s): amp0 = h@w_lin.T+b_lin; audio MLP -> amp1; norms; phases;
//     tpr/tpi x r1/i1 outer products -> X=[real|imag] row; weight scalar.
// =====================================================================
__global__ __launch_bounds__(256) void k3_mix(
    const int* __restrict__ widx, const float* __restrict__ audio,
    const float* __restrict__ ph0t, const float* __restrict__ ph1t,
    const float* __restrict__ w_lin, const float* __restrict__ b_lin,
    const float* __restrict__ w1, const float* __restrict__ b1,
    const float* __restrict__ w2, const float* __restrict__ b2,
    const float* __restrict__ w3, const float* __restrict__ b3,
    const float* __restrict__ modw, float* __restrict__ ws)
{
  const int bs = blockIdx.x;
  const int t = threadIdx.x;
  __shared__ float amp0[16], a1s[16], a2s[16], amp1[16];
  __shared__ float tpr[16], tpi[16], r1s[16], i1s[16];
  __shared__ float nn[2];

  const float* hrow = ws + HOUT_OFF + bs * 128;
  if (t < 16) {
    float acc = b_lin[t];
    for (int u = 0; u < 128; ++u) acc = fmaf(hrow[u], w_lin[t * 128 + u], acc);
    amp0[t] = acc;
  } else if (t >= 64 && t < 80) {
    int d = t - 64;
    float acc = b1[d];
    for (int k = 0; k < 74; ++k) acc = fmaf(audio[bs * 74 + k], w1[d * 74 + k], acc);
    a1s[d] = fmaxf(acc, 0.f);
  }
  __syncthreads();
  if (t < 16) {
    float acc = b2[t];
    #pragma unroll
    for (int k = 0; k < 16; ++k) acc = fmaf(a1s[k], w2[t * 16 + k], acc);
    a2s[t] = fmaxf(acc, 0.f);
  }
  __syncthreads();
  if (t < 16) {
    float acc = b3[t];
    #pragma unroll
    for (int k = 0; k < 16; ++k) acc = fmaf(a2s[k], w3[t * 16 + k], acc);
    amp1[t] = fmaxf(acc, 0.f);
  }
  __syncthreads();
  if (t == 0) {
    float sq = 0.f;
    #pragma unroll
    for (int d = 0; d < 16; ++d) sq += amp0[d] * amp0[d];
    nn[0] = sqrtf(sq);
  } else if (t == 64) {
    float sq = 0.f;
    #pragma unroll
    for (int d = 0; d < 16; ++d) sq += amp1[d] * amp1[d];
    nn[1] = sqrtf(sq);
  }
  __syncthreads();
  const int word = widx[bs];
  if (t < 16) {
    float k0 = amp0[t] / (nn[0] + 1e-10f);
    float ph = ph0t[word * 16 + t];
    float cc = cosf(ph), ssn = sinf(ph);
    tpr[t] = k0 * (cc - ssn);       // r0 - i0
    tpi[t] = k0 * (cc + ssn);       // r0 + i0
  } else if (t >= 64 && t < 80) {
    int d = t - 64;
    float k1 = amp1[d] / (nn[1] + 1e-10f);
    float ph = ph1t[word * 16 + d];
    r1s[d] = k1 * cosf(ph);
    i1s[d] = k1 * sinf(ph);
  } else if (t == 128) {
    float e0 = __expf(modw[0]), e1 = __expf(modw[1]);
    float mw0 = e0 / (e0 + e1);
    ws[WT_OFF + bs] = mw0 * nn[0] + (1.f - mw0) * nn[1];
  }
  __syncthreads();
  const int i2 = t >> 4, j2 = t & 15;
  float rr = tpr[i2] * r1s[j2] - tpi[i2] * i1s[j2];
  float im = tpr[i2] * i1s[j2] + tpi[i2] * r1s[j2];
  float* X = ws + XMAT_OFF;
  X[bs * 512 + t] = rr;
  X[bs * 512 + 256 + t] = im;
}

// =====================================================================
// K4: P[r][c] = sum_k X[r][k] * V''[c][k]   (1024 x 256, k=512 split x4)
//     writes per-kq partials; 64x64 tiles, 4x4 micro.
// =====================================================================
__global__ __launch_bounds__(256) void k4_meas(float* __restrict__ ws)
{
  const int bid = blockIdx.x, t = threadIdx.x;
  const int rb = bid & 15, cb = (bid >> 4) & 3, kq = bid >> 6;
  const int R = rb * 64, C = cb * 64;
  const float* X = ws + XMAT_OFF;
  const float* V = ws + VPP_OFF;
  __shared__ alignas(16) float Xs[32][68];
  __shared__ alignas(16) float Vs[32][68];
  float acc[4][4] = {};
  const int r0 = (t & 15) * 4, j0 = (t >> 4) * 4;

  for (int kt = 0; kt < 4; ++kt) {
    #pragma unroll
    for (int pass = 0; pass < 2; ++pass) {
      int rr = (t >> 3) + pass * 32;
      int kk4 = (t & 7) * 4;
      int gk = kq * 128 + kt * 32 + kk4;
      float4 xv = *(const float4*)&X[(R + rr) * 512 + gk];
      float4 vv = *(const float4*)&V[(C + rr) * 512 + gk];
      Xs[kk4 + 0][rr] = xv.x; Xs[kk4 + 1][rr] = xv.y;
      Xs[kk4 + 2][rr] = xv.z; Xs[kk4 + 3][rr] = xv.w;
      Vs[kk4 + 0][rr] = vv.x; Vs[kk4 + 1][rr] = vv.y;
      Vs[kk4 + 2][rr] = vv.z; Vs[kk4 + 3][rr] = vv.w;
    }
    __syncthreads();
    #pragma unroll
    for (int k = 0; k < 32; ++k) {
      float4 a4 = *(const float4*)&Xs[k][r0];
      float4 w4 = *(const float4*)&Vs[k][j0];
      float ar[4] = {a4.x, a4.y, a4.z, a4.w};
      float wr[4] = {w4.x, w4.y, w4.z, w4.w};
      #pragma unroll
      for (int i2 = 0; i2 < 4; ++i2)
        #pragma unroll
        for (int j2 = 0; j2 < 4; ++j2)
          acc[i2][j2] = fmaf(ar[i2], wr[j2], acc[i2][j2]);
    }
    __syncthreads();
  }
  float* Pp = ws + PP_OFF + (unsigned)kq * PP_HALF;
  #pragma unroll
  for (int i2 = 0; i2 < 4; ++i2) {
    float4 v = make_float4(acc[i2][0], acc[i2][1], acc[i2][2], acc[i2][3]);
    *(float4*)&Pp[(R + r0 + i2) * 256 + C + j0] = v;
  }
}

// =====================================================================
// K5: per b: p[s][u] = P[2u]^2 + P[2u+1]^2 (sum kq partials);
//     n-gram softmax mixes (n=1,3 zero-padded), max-pool, final MLP.
// =====================================================================
__global__ __launch_bounds__(512) void k5_final(
    const float* __restrict__ fw1, const float* __restrict__ fb1,
    const float* __restrict__ fw2, const float* __restrict__ fb2,
    const float* __restrict__ fw3, const float* __restrict__ fb3,
    const float* __restrict__ ws, float* __restrict__ out)
{
  const int b = blockIdx.x, t = threadIdx.x;
  const int u = t & 127, sg = t >> 7;      // sg 0..3
  __shared__ float ewt[34];
  __shared__ float pl[32][128];
  __shared__ float fred[4][128];
  __shared__ float feat[128], y1[64], y2[64];
  if (t < 32) ewt[t] = __expf(ws[WT_OFF + b * 32 + t]);
  if (t >= 32 && t < 34) ewt[t] = 1.f;
  __syncthreads();

  const float* Pp = ws + PP_OFF;
  #pragma unroll
  for (int i = 0; i < 8; ++i) {
    int s = sg * 8 + i;
    int bs = b * 32 + s;
    float A = 0.f, Bv = 0.f;
    #pragma unroll
    for (int kq = 0; kq < 4; ++kq) {
      A  += Pp[kq * PP_HALF + bs * 256 + 2 * u];
      Bv += Pp[kq * PP_HALF + bs * 256 + 2 * u + 1];
    }
    pl[s][u] = A * A + Bv * Bv;
  }
  __syncthreads();

  float m = -1e30f;
  #pragma unroll
  for (int i = 0; i < 8; ++i) {
    int s = sg * 8 + i;
    float p0 = pl[s][u];
    m = fmaxf(m, p0);                       // n=1 (softmax of 1 elem = 1)
    float e0 = ewt[s], e1 = ewt[s + 1], e2 = ewt[s + 2];
    float num = e0 * p0;
    if (s + 1 < 32) num += e1 * pl[s + 1][u];
    if (s + 2 < 32) num += e2 * pl[s + 2][u];
    m = fmaxf(m, num / (e0 + e1 + e2));
  }
  fred[sg][u] = m;
  __syncthreads();
  if (t < 128)
    feat[t] = fmaxf(fmaxf(fred[0][t], fred[1][t]), fmaxf(fred[2][t], fred[3][t]));
  __syncthreads();
  if (t < 64) {
    float acc = fb1[t];
    for (int k = 0; k < 128; ++k) acc = fmaf(feat[k], fw1[t * 128 + k], acc);
    y1[t] = fmaxf(acc, 0.f);
  }
  __syncthreads();
  if (t < 64) {
    float acc = fb2[t];
    #pragma unroll
    for (int k = 0; k < 64; ++k) acc = fmaf(y1[k], fw2[t * 64 + k], acc);
    y2[t] = fmaxf(acc, 0.f);
  }
  __syncthreads();
  if (t == 0) {
    float acc = fb3[0];
    #pragma unroll
    for (int k = 0; k < 64; ++k) acc = fmaf(y2[k], fw3[k], acc);
    out[b] = acc;
  }
}

// =====================================================================
extern "C" void kernel_launch(void* const* d_in, const int* in_sizes, int n_in,
                              void* d_out, int out_size, void* d_ws, size_t ws_size,
                              hipStream_t stream) {
  const int*   widx  = (const int*)d_in[0];
  const float* audio = (const float*)d_in[1];
  const float* lut   = (const float*)d_in[2];
  const float* ph0   = (const float*)d_in[3];
  const float* ph1   = (const float*)d_in[4];
  const float* w_ih  = (const float*)d_in[5];
  const float* w_hh  = (const float*)d_in[6];
  const float* b_ih  = (const float*)d_in[7];
  const float* b_hh  = (const float*)d_in[8];
  const float* w_lin = (const float*)d_in[9];
  const float* b_lin = (const float*)d_in[10];
  const float* w1    = (const float*)d_in[11];
  const float* b1    = (const float*)d_in[12];
  const float* w2    = (const float*)d_in[13];
  const float* b2    = (const float*)d_in[14];
  const float* w3    = (const float*)d_in[15];
  const float* b3    = (const float*)d_in[16];
  const float* modw  = (const float*)d_in[17];
  const float* mr    = (const float*)d_in[18];
  const float* mi    = (const float*)d_in[19];
  const float* fw1   = (const float*)d_in[20];
  const float* fb1   = (const float*)d_in[21];
  const float* fw2   = (const float*)d_in[22];
  const float* fb2   = (const float*)d_in[23];
  const float* fw3   = (const float*)d_in[24];
  const float* fb3   = (const float*)d_in[25];
  float* ws  = (float*)d_ws;
  float* out = (float*)d_out;

  k1_xw_gemm<<<dim3(384), dim3(256), 0, stream>>>(widx, lut, w_ih, b_ih, b_hh, mr, mi, ws);
  k2_lstm<<<dim3(32), dim3(640), 0, stream>>>(w_hh, ws);
  k3_mix<<<dim3(1024), dim3(256), 0, stream>>>(widx, audio, ph0, ph1, w_lin, b_lin,
                                               w1, b1, w2, b2, w3, b3, modw, ws);
  k4_meas<<<dim3(256), dim3(256), 0, stream>>>(ws);
  k5_final<<<dim3(32), dim3(512), 0, stream>>>(fw1, fb1, fw2, fb2, fw3, fb3, ws, out);
}